// Round 4
// baseline (1099.780 us; speedup 1.0000x reference)
//
#include <hip/hip_runtime.h>

typedef __bf16 bf16x8 __attribute__((ext_vector_type(8)));
typedef float f32x4 __attribute__((ext_vector_type(4)));
typedef unsigned short u16;
typedef unsigned int u32;

#define MFMA(a, b, c) __builtin_amdgcn_mfma_f32_16x16x32_bf16((a), (b), (c), 0, 0, 0)

// B=2, L=2048, D=1024, H=16, DH=64
// d_out: out [B,L,D] (4,194,304 f32) then attn [B,H,L,L] (134,217,728 f32)

__device__ __forceinline__ u16 f2bf(float f) {
  u32 u = __float_as_uint(f);
  return (u16)((u + 0x7fffu + ((u >> 16) & 1u)) >> 16);
}

// ---------------- merged prep: 5x fp32->bf16 convert + conv weight transpose ----------------
__global__ __launch_bounds__(256) void prep_all(
    const float4* __restrict__ src, const float4* __restrict__ wq,
    const float4* __restrict__ wk, const float4* __restrict__ wv,
    const float4* __restrict__ wo, const float* __restrict__ cw,
    uint2* __restrict__ srcb, uint2* __restrict__ wqb, uint2* __restrict__ wkb,
    uint2* __restrict__ wvb, uint2* __restrict__ wob, float* __restrict__ cwT) {
  int bx = blockIdx.x;
  if (bx < 8192) {
    const float4* in;
    uint2* out;
    int base;
    if (bx < 4096) { in = src; out = srcb; base = 0; }
    else if (bx < 5120) { in = wq; out = wqb; base = 4096; }
    else if (bx < 6144) { in = wk; out = wkb; base = 5120; }
    else if (bx < 7168) { in = wv; out = wvb; base = 6144; }
    else { in = wo; out = wob; base = 7168; }
    int i = (bx - base) * 256 + threadIdx.x;
    float4 v = in[i];
    uint2 o;
    o.x = (u32)f2bf(v.x) | ((u32)f2bf(v.y) << 16);
    o.y = (u32)f2bf(v.z) | ((u32)f2bf(v.w) << 16);
    out[i] = o;
  } else {
    int i = (bx - 8192) * 256 + threadIdx.x;
    int h = i / 3072;
    int j = (i - h * 3072) >> 10;
    int d = i & 1023;
    cwT[i] = cw[(h * 1024 + d) * 3 + j];
  }
}

// ---------------- saliency conv, 4-way D-split for occupancy ----------------
// block 256 = (dc 4) x (li 4) x (h 16); each thread sums 256 d for (b,l,h,dc); LDS combine.
__global__ __launch_bounds__(256) void conv_sal_k(const float* __restrict__ src,
                                                  const float* __restrict__ cwT,
                                                  const float* __restrict__ cb,
                                                  float* __restrict__ sal) {
  __shared__ float part[4][16][17];
  const int t = threadIdx.x;
  const int h = t & 15;
  const int li = (t >> 4) & 3;
  const int dc = t >> 6;  // wave-uniform
  const int b = blockIdx.y;
  const int l = blockIdx.x * 4 + li;
  float4 acc = {0.f, 0.f, 0.f, 0.f};
#pragma unroll
  for (int j = 0; j < 3; j++) {
    int ls = l + j - 1;
    if (ls < 0 || ls >= 2048) continue;
    const float4* sp = (const float4*)(src + ((size_t)b * 2048 + ls) * 1024 + dc * 256);
    const float4* wp = (const float4*)(cwT + (h * 3 + j) * 1024 + dc * 256);
    for (int d = 0; d < 64; d++) {
      float4 a = sp[d], w = wp[d];
      acc.x += a.x * w.x;
      acc.y += a.y * w.y;
      acc.z += a.z * w.z;
      acc.w += a.w * w.w;
    }
  }
  part[dc][li][h] = (acc.x + acc.y) + (acc.z + acc.w);
  __syncthreads();
  if (dc == 0) {
    float s = cb[h] + ((part[0][li][h] + part[1][li][h]) + (part[2][li][h] + part[3][li][h]));
    sal[(b * 16 + h) * 2048 + l] = s;
  }
}

// ---------------- LDS-tiled GEMM core: 128x128 tile, BK=32, reg-staged ----------------
__device__ __forceinline__ void gemm_core(const u16* __restrict__ Xg, const u16* __restrict__ Wg,
                                          int mblk, int nblk, u16* smA, u16* smB,
                                          f32x4 acc[4][4]) {
  const int t = threadIdx.x;
  const int lane = t & 63, wid = t >> 6;
  const int cl = lane & 15, gp = lane >> 4;
  const int r0 = t >> 2, cc = (t & 3) * 8;
  const u16* gA0 = Xg + (size_t)(mblk + r0) * 1024 + cc;
  const u16* gB0 = Wg + (size_t)(nblk + r0) * 1024 + cc;
  u16* lA0 = smA + t * 8;
  u16* lB0 = smB + t * 8;
  const u16* rA = smA + ((wid >> 1) * 64 + cl) * 32 + gp * 8;
  const u16* rB = smB + ((wid & 1) * 64 + cl) * 32 + gp * 8;
  for (int k0 = 0; k0 < 1024; k0 += 32) {
    bf16x8 sa0 = *(const bf16x8*)(gA0 + k0);
    bf16x8 sa1 = *(const bf16x8*)(gA0 + 64 * 1024 + k0);
    bf16x8 sb0 = *(const bf16x8*)(gB0 + k0);
    bf16x8 sb1 = *(const bf16x8*)(gB0 + 64 * 1024 + k0);
    __syncthreads();
    *(bf16x8*)lA0 = sa0;
    *(bf16x8*)(lA0 + 2048) = sa1;
    *(bf16x8*)lB0 = sb0;
    *(bf16x8*)(lB0 + 2048) = sb1;
    __syncthreads();
    bf16x8 a[4], b[4];
#pragma unroll
    for (int i = 0; i < 4; i++) {
      a[i] = *(const bf16x8*)(rA + i * 512);
      b[i] = *(const bf16x8*)(rB + i * 512);
    }
#pragma unroll
    for (int tm = 0; tm < 4; tm++)
#pragma unroll
      for (int tn = 0; tn < 4; tn++) acc[tm][tn] = MFMA(a[tm], b[tn], acc[tm][tn]);
  }
}

// ---------------- fused QKV projection GEMM ----------------
__global__ __launch_bounds__(256) void qkv_gemm(
    const u16* __restrict__ Xb, const u16* __restrict__ Wqb, const u16* __restrict__ Wkb,
    const u16* __restrict__ Wvb, const float* __restrict__ bq, const float* __restrict__ bk,
    const float* __restrict__ bv, u16* __restrict__ Qb, u16* __restrict__ Kb,
    u16* __restrict__ Vt) {
  __shared__ __align__(16) u16 smA[4096], smB[4096];
  const int seg = blockIdx.x >> 3;
  const u16* __restrict__ W = (seg == 0) ? Wqb : (seg == 1) ? Wkb : Wvb;
  const float* __restrict__ bias = (seg == 0) ? bq : (seg == 1) ? bk : bv;
  const int lane = threadIdx.x & 63, wid = threadIdx.x >> 6;
  const int cl = lane & 15, gp = lane >> 4;
  const int mblk = blockIdx.y * 128, nblk = (blockIdx.x & 7) * 128;
  const int m0 = mblk + (wid >> 1) * 64;
  const int n0 = nblk + (wid & 1) * 64;
  f32x4 acc[4][4] = {};
  gemm_core(Xb, W, mblk, nblk, smA, smB, acc);
#pragma unroll
  for (int tn = 0; tn < 4; tn++) {
    int col = n0 + tn * 16 + cl;
    float bv_ = bias[col];
    int hh = col >> 6, dh = col & 63;
#pragma unroll
    for (int tm = 0; tm < 4; tm++) {
#pragma unroll
      for (int r = 0; r < 4; r++) {
        int row = m0 + tm * 16 + gp * 4 + r;
        u16 hv = f2bf(acc[tm][tn][r] + bv_);
        int bb = row >> 11, l = row & 2047;
        if (seg == 0)
          Qb[(((size_t)(bb * 16 + hh) * 2048 + l) << 6) + dh] = hv;
        else if (seg == 1)
          Kb[(((size_t)(bb * 16 + hh) * 2048 + l) << 6) + dh] = hv;
        else
          Vt[((size_t)(bb * 16 + hh) * 64 + dh) * 2048 + l] = hv;
      }
    }
  }
}

// ---------------- out projection GEMM ----------------
__global__ __launch_bounds__(256) void out_gemm(const u16* __restrict__ Xb,
                                                const u16* __restrict__ W,
                                                const float* __restrict__ bias,
                                                float* __restrict__ Y) {
  __shared__ __align__(16) u16 smA[4096], smB[4096];
  const int lane = threadIdx.x & 63, wid = threadIdx.x >> 6;
  const int cl = lane & 15, gp = lane >> 4;
  const int mblk = blockIdx.y * 128, nblk = blockIdx.x * 128;
  const int m0 = mblk + (wid >> 1) * 64;
  const int n0 = nblk + (wid & 1) * 64;
  f32x4 acc[4][4] = {};
  gemm_core(Xb, W, mblk, nblk, smA, smB, acc);
#pragma unroll
  for (int tn = 0; tn < 4; tn++) {
    int col = n0 + tn * 16 + cl;
    float bv_ = bias[col];
#pragma unroll
    for (int tm = 0; tm < 4; tm++)
#pragma unroll
      for (int r = 0; r < 4; r++) {
        int row = m0 + tm * 16 + gp * 4 + r;
        Y[(size_t)row * 1024 + col] = acc[tm][tn][r] + bv_;
      }
  }
}

// ---------------- fused flash attention, barrier-free, 2-wave blocks ----------------
// wave handles 16 queries; block = 2 waves = 32 queries of one (b,h); grid (32, 64).
// pbuf is PER-WAVE private: only intra-wave DS ordering needed (lgkmcnt), no s_barrier.
__global__ __launch_bounds__(128, 6) void flash_fused(const u16* __restrict__ Qb,
                                                      const u16* __restrict__ Kb,
                                                      const u16* __restrict__ Vt,
                                                      const float* __restrict__ sal,
                                                      float* __restrict__ attn,
                                                      u16* __restrict__ Ob) {
  __shared__ __align__(16) u16 pbuf[2][16][72];  // per-wave 16x64 P tile, padded stride 72
  const int bh = blockIdx.x;
  const int b = bh >> 4, h = bh & 15;
  const int lane = threadIdx.x & 63, wid = threadIdx.x >> 6;
  const int cl = lane & 15, gp = lane >> 4;
  const int q0 = blockIdx.y * 32 + wid * 16;
  const u16* Qh = Qb + (size_t)bh * 2048 * 64;
  const u16* Kh = Kb + (size_t)bh * 2048 * 64;
  const u16* Vh = Vt + (size_t)bh * 64 * 2048;
  const float* salh = sal + bh * 2048;
  bf16x8 aQ0 = *(const bf16x8*)(Qh + (size_t)(q0 + cl) * 64 + gp * 8);
  bf16x8 aQ1 = *(const bf16x8*)(Qh + (size_t)(q0 + cl) * 64 + 32 + gp * 8);

  // ---- pass 1: QK^T -> LANE-LOCAL running (m, l); cross-lane reduce deferred to end.
  float ml[4], ll[4];
#pragma unroll
  for (int r = 0; r < 4; r++) { ml[r] = -1e30f; ll[r] = 0.f; }
  for (int kb = 0; kb < 2048; kb += 64) {
    f32x4 st[4];
#pragma unroll
    for (int tn = 0; tn < 4; tn++) {
      const u16* kp = Kh + (size_t)(kb + tn * 16 + cl) * 64 + gp * 8;
      f32x4 s = {};
      s = MFMA(aQ0, *(const bf16x8*)kp, s);
      s = MFMA(aQ1, *(const bf16x8*)(kp + 32), s);
      st[tn] = s;
    }
#pragma unroll
    for (int tn = 0; tn < 4; tn++) {
      float sv = salh[kb + tn * 16 + cl];
#pragma unroll
      for (int r = 0; r < 4; r++) st[tn][r] = st[tn][r] * 0.125f + sv;
    }
#pragma unroll
    for (int r = 0; r < 4; r++) {
      float v = fmaxf(fmaxf(st[0][r], st[1][r]), fmaxf(st[2][r], st[3][r]));
      float mn = fmaxf(ml[r], v);
      float alpha = __expf(ml[r] - mn);
      ml[r] = mn;
      float s0 = __expf(st[0][r] - mn) + __expf(st[1][r] - mn) + __expf(st[2][r] - mn) +
                 __expf(st[3][r] - mn);
      ll[r] = ll[r] * alpha + s0;
    }
  }
  // end-of-pass cross-lane reduce (16 lanes sharing gp hold different cols of same rows)
  float m[4], il[4];
#pragma unroll
  for (int r = 0; r < 4; r++) {
    float mr = ml[r];
    mr = fmaxf(mr, __shfl_xor(mr, 1));
    mr = fmaxf(mr, __shfl_xor(mr, 2));
    mr = fmaxf(mr, __shfl_xor(mr, 4));
    mr = fmaxf(mr, __shfl_xor(mr, 8));
    float lr = ll[r] * __expf(ml[r] - mr);
    lr += __shfl_xor(lr, 1);
    lr += __shfl_xor(lr, 2);
    lr += __shfl_xor(lr, 4);
    lr += __shfl_xor(lr, 8);
    m[r] = mr;
    il[r] = 1.0f / lr;
  }

  // ---- pass 2: recompute S, stream normalized attn, accumulate O. NO barriers.
  f32x4 oacc[4] = {};
  float* arow = attn + (size_t)bh * 2048 * 2048;
  u16* pw = &pbuf[wid][0][0];
  for (int kb = 0; kb < 2048; kb += 64) {
    f32x4 st[4];
#pragma unroll
    for (int tn = 0; tn < 4; tn++) {
      const u16* kp = Kh + (size_t)(kb + tn * 16 + cl) * 64 + gp * 8;
      f32x4 s = {};
      s = MFMA(aQ0, *(const bf16x8*)kp, s);
      s = MFMA(aQ1, *(const bf16x8*)(kp + 32), s);
      st[tn] = s;
    }
#pragma unroll
    for (int tn = 0; tn < 4; tn++) {
      float sv = salh[kb + tn * 16 + cl];
#pragma unroll
      for (int r = 0; r < 4; r++) {
        float p = __expf(st[tn][r] * 0.125f + sv - m[r]);
        arow[(size_t)(q0 + gp * 4 + r) * 2048 + kb + tn * 16 + cl] = p * il[r];
        pw[(gp * 4 + r) * 72 + tn * 16 + cl] = f2bf(p);
      }
    }
    // intra-wave DS write->read ordering only (pbuf is per-wave private)
    asm volatile("s_waitcnt lgkmcnt(0)" ::: "memory");
    __builtin_amdgcn_sched_barrier(0);
    bf16x8 aP0 = *(const bf16x8*)(pw + cl * 72 + gp * 8);
    bf16x8 aP1 = *(const bf16x8*)(pw + cl * 72 + 32 + gp * 8);
    asm volatile("" ::: "memory");  // keep next-iter ds_writes after these ds_reads
#pragma unroll
    for (int tn = 0; tn < 4; tn++) {
      const u16* vp = Vh + (size_t)(tn * 16 + cl) * 2048 + kb + gp * 8;
      oacc[tn] = MFMA(aP0, *(const bf16x8*)vp, oacc[tn]);
      oacc[tn] = MFMA(aP1, *(const bf16x8*)(vp + 32), oacc[tn]);
    }
  }
#pragma unroll
  for (int tn = 0; tn < 4; tn++) {
    int d = h * 64 + tn * 16 + cl;
#pragma unroll
    for (int r = 0; r < 4; r++) {
      int q = q0 + gp * 4 + r;
      Ob[((size_t)(b * 2048 + q)) * 1024 + d] = f2bf(oacc[tn][r] * il[r]);
    }
  }
}

// ---------------- launch ----------------
extern "C" void kernel_launch(void* const* d_in, const int* in_sizes, int n_in,
                              void* d_out, int out_size, void* d_ws, size_t ws_size,
                              hipStream_t stream) {
  const float* src = (const float*)d_in[0];
  const float* Wq = (const float*)d_in[1];
  const float* bq = (const float*)d_in[2];
  const float* Wk = (const float*)d_in[3];
  const float* bk = (const float*)d_in[4];
  const float* Wv = (const float*)d_in[5];
  const float* bv = (const float*)d_in[6];
  const float* Wo = (const float*)d_in[7];
  const float* bo = (const float*)d_in[8];
  const float* cw = (const float*)d_in[9];
  const float* cb = (const float*)d_in[10];

  char* ws = (char*)d_ws;
  u16* srcb = (u16*)(ws + 0);          // 8,388,608 B
  u16* wqb = (u16*)(ws + 8388608);     // 2,097,152 B
  u16* wkb = (u16*)(ws + 10485760);
  u16* wvb = (u16*)(ws + 12582912);
  u16* wob = (u16*)(ws + 14680064);
  u16* Qb = (u16*)(ws + 16777216);     // 8,388,608 B  [B,H,L,64] bf16
  u16* Kb = (u16*)(ws + 25165824);
  u16* Vt = (u16*)(ws + 33554432);     // [B,H,64,L] bf16
  u16* Ob = (u16*)(ws + 41943040);     // [B,L,D] bf16
  float* cwT = (float*)(ws + 50331648);
  float* sal = (float*)(ws + 50528256);  // end 50,790,400

  float* outp = (float*)d_out;
  float* attn = (float*)d_out + 4194304;

  prep_all<<<8384, 256, 0, stream>>>((const float4*)src, (const float4*)Wq, (const float4*)Wk,
                                     (const float4*)Wv, (const float4*)Wo, cw,
                                     (uint2*)srcb, (uint2*)wqb, (uint2*)wkb, (uint2*)wvb,
                                     (uint2*)wob, cwT);
  conv_sal_k<<<dim3(512, 2), 256, 0, stream>>>(src, cwT, cb, sal);
  qkv_gemm<<<dim3(24, 32), 256, 0, stream>>>(srcb, wqb, wkb, wvb, bq, bk, bv, Qb, Kb, Vt);
  flash_fused<<<dim3(32, 64), 128, 0, stream>>>(Qb, Kb, Vt, sal, attn, Ob);
  out_gemm<<<dim3(8, 32), 256, 0, stream>>>(Ob, wob, bo, outp);
}

// Round 6
// 1055.783 us; speedup vs baseline: 1.0417x; 1.0417x over previous
//
#include <hip/hip_runtime.h>

typedef __bf16 bf16x8 __attribute__((ext_vector_type(8)));
typedef float f32x4 __attribute__((ext_vector_type(4)));
typedef unsigned short u16;
typedef unsigned int u32;

#define MFMA(a, b, c) __builtin_amdgcn_mfma_f32_16x16x32_bf16((a), (b), (c), 0, 0, 0)

// B=2, L=2048, D=1024, H=16, DH=64
// d_out: out [B,L,D] (4,194,304 f32) then attn [B,H,L,L] (134,217,728 f32)

__device__ __forceinline__ u16 f2bf(float f) {
  u32 u = __float_as_uint(f);
  return (u16)((u + 0x7fffu + ((u >> 16) & 1u)) >> 16);
}

// ---------------- merged prep: 5x fp32->bf16 convert + conv weight transpose ----------------
__global__ __launch_bounds__(256) void prep_all(
    const float4* __restrict__ src, const float4* __restrict__ wq,
    const float4* __restrict__ wk, const float4* __restrict__ wv,
    const float4* __restrict__ wo, const float* __restrict__ cw,
    uint2* __restrict__ srcb, uint2* __restrict__ wqb, uint2* __restrict__ wkb,
    uint2* __restrict__ wvb, uint2* __restrict__ wob, float* __restrict__ cwT) {
  int bx = blockIdx.x;
  if (bx < 8192) {
    const float4* in;
    uint2* out;
    int base;
    if (bx < 4096) { in = src; out = srcb; base = 0; }
    else if (bx < 5120) { in = wq; out = wqb; base = 4096; }
    else if (bx < 6144) { in = wk; out = wkb; base = 5120; }
    else if (bx < 7168) { in = wv; out = wvb; base = 6144; }
    else { in = wo; out = wob; base = 7168; }
    int i = (bx - base) * 256 + threadIdx.x;
    float4 v = in[i];
    uint2 o;
    o.x = (u32)f2bf(v.x) | ((u32)f2bf(v.y) << 16);
    o.y = (u32)f2bf(v.z) | ((u32)f2bf(v.w) << 16);
    out[i] = o;
  } else {
    int i = (bx - 8192) * 256 + threadIdx.x;
    int h = i / 3072;
    int j = (i - h * 3072) >> 10;
    int d = i & 1023;
    cwT[i] = cw[(h * 1024 + d) * 3 + j];
  }
}

// ---------------- saliency conv, 4-way D-split for occupancy ----------------
__global__ __launch_bounds__(256) void conv_sal_k(const float* __restrict__ src,
                                                  const float* __restrict__ cwT,
                                                  const float* __restrict__ cb,
                                                  float* __restrict__ sal) {
  __shared__ float part[4][16][17];
  const int t = threadIdx.x;
  const int h = t & 15;
  const int li = (t >> 4) & 3;
  const int dc = t >> 6;  // wave-uniform
  const int b = blockIdx.y;
  const int l = blockIdx.x * 4 + li;
  float4 acc = {0.f, 0.f, 0.f, 0.f};
#pragma unroll
  for (int j = 0; j < 3; j++) {
    int ls = l + j - 1;
    if (ls < 0 || ls >= 2048) continue;
    const float4* sp = (const float4*)(src + ((size_t)b * 2048 + ls) * 1024 + dc * 256);
    const float4* wp = (const float4*)(cwT + (h * 3 + j) * 1024 + dc * 256);
    for (int d = 0; d < 64; d++) {
      float4 a = sp[d], w = wp[d];
      acc.x += a.x * w.x;
      acc.y += a.y * w.y;
      acc.z += a.z * w.z;
      acc.w += a.w * w.w;
    }
  }
  part[dc][li][h] = (acc.x + acc.y) + (acc.z + acc.w);
  __syncthreads();
  if (dc == 0) {
    float s = cb[h] + ((part[0][li][h] + part[1][li][h]) + (part[2][li][h] + part[3][li][h]));
    sal[(b * 16 + h) * 2048 + l] = s;
  }
}

// ---------------- LDS-tiled GEMM core: 128x128 tile, BK=32, reg-staged ----------------
__device__ __forceinline__ void gemm_core(const u16* __restrict__ Xg, const u16* __restrict__ Wg,
                                          int mblk, int nblk, u16* smA, u16* smB,
                                          f32x4 acc[4][4]) {
  const int t = threadIdx.x;
  const int lane = t & 63, wid = t >> 6;
  const int cl = lane & 15, gp = lane >> 4;
  const int r0 = t >> 2, cc = (t & 3) * 8;
  const u16* gA0 = Xg + (size_t)(mblk + r0) * 1024 + cc;
  const u16* gB0 = Wg + (size_t)(nblk + r0) * 1024 + cc;
  u16* lA0 = smA + t * 8;
  u16* lB0 = smB + t * 8;
  const u16* rA = smA + ((wid >> 1) * 64 + cl) * 32 + gp * 8;
  const u16* rB = smB + ((wid & 1) * 64 + cl) * 32 + gp * 8;
  for (int k0 = 0; k0 < 1024; k0 += 32) {
    bf16x8 sa0 = *(const bf16x8*)(gA0 + k0);
    bf16x8 sa1 = *(const bf16x8*)(gA0 + 64 * 1024 + k0);
    bf16x8 sb0 = *(const bf16x8*)(gB0 + k0);
    bf16x8 sb1 = *(const bf16x8*)(gB0 + 64 * 1024 + k0);
    __syncthreads();
    *(bf16x8*)lA0 = sa0;
    *(bf16x8*)(lA0 + 2048) = sa1;
    *(bf16x8*)lB0 = sb0;
    *(bf16x8*)(lB0 + 2048) = sb1;
    __syncthreads();
    bf16x8 a[4], b[4];
#pragma unroll
    for (int i = 0; i < 4; i++) {
      a[i] = *(const bf16x8*)(rA + i * 512);
      b[i] = *(const bf16x8*)(rB + i * 512);
    }
#pragma unroll
    for (int tm = 0; tm < 4; tm++)
#pragma unroll
      for (int tn = 0; tn < 4; tn++) acc[tm][tn] = MFMA(a[tm], b[tn], acc[tm][tn]);
  }
}

// ---------------- fused QKV projection GEMM ----------------
__global__ __launch_bounds__(256) void qkv_gemm(
    const u16* __restrict__ Xb, const u16* __restrict__ Wqb, const u16* __restrict__ Wkb,
    const u16* __restrict__ Wvb, const float* __restrict__ bq, const float* __restrict__ bk,
    const float* __restrict__ bv, u16* __restrict__ Qb, u16* __restrict__ Kb,
    u16* __restrict__ Vt) {
  __shared__ __align__(16) u16 smA[4096], smB[4096];
  const int seg = blockIdx.x >> 3;
  const u16* __restrict__ W = (seg == 0) ? Wqb : (seg == 1) ? Wkb : Wvb;
  const float* __restrict__ bias = (seg == 0) ? bq : (seg == 1) ? bk : bv;
  const int lane = threadIdx.x & 63, wid = threadIdx.x >> 6;
  const int cl = lane & 15, gp = lane >> 4;
  const int mblk = blockIdx.y * 128, nblk = (blockIdx.x & 7) * 128;
  const int m0 = mblk + (wid >> 1) * 64;
  const int n0 = nblk + (wid & 1) * 64;
  f32x4 acc[4][4] = {};
  gemm_core(Xb, W, mblk, nblk, smA, smB, acc);
#pragma unroll
  for (int tn = 0; tn < 4; tn++) {
    int col = n0 + tn * 16 + cl;
    float bv_ = bias[col];
    int hh = col >> 6, dh = col & 63;
#pragma unroll
    for (int tm = 0; tm < 4; tm++) {
#pragma unroll
      for (int r = 0; r < 4; r++) {
        int row = m0 + tm * 16 + gp * 4 + r;
        u16 hv = f2bf(acc[tm][tn][r] + bv_);
        int bb = row >> 11, l = row & 2047;
        if (seg == 0)
          Qb[(((size_t)(bb * 16 + hh) * 2048 + l) << 6) + dh] = hv;
        else if (seg == 1)
          Kb[(((size_t)(bb * 16 + hh) * 2048 + l) << 6) + dh] = hv;
        else
          Vt[((size_t)(bb * 16 + hh) * 64 + dh) * 2048 + l] = hv;
      }
    }
  }
}

// ---------------- out projection GEMM ----------------
__global__ __launch_bounds__(256) void out_gemm(const u16* __restrict__ Xb,
                                                const u16* __restrict__ W,
                                                const float* __restrict__ bias,
                                                float* __restrict__ Y) {
  __shared__ __align__(16) u16 smA[4096], smB[4096];
  const int lane = threadIdx.x & 63, wid = threadIdx.x >> 6;
  const int cl = lane & 15, gp = lane >> 4;
  const int mblk = blockIdx.y * 128, nblk = blockIdx.x * 128;
  const int m0 = mblk + (wid >> 1) * 64;
  const int n0 = nblk + (wid & 1) * 64;
  f32x4 acc[4][4] = {};
  gemm_core(Xb, W, mblk, nblk, smA, smB, acc);
#pragma unroll
  for (int tn = 0; tn < 4; tn++) {
    int col = n0 + tn * 16 + cl;
    float bv_ = bias[col];
#pragma unroll
    for (int tm = 0; tm < 4; tm++)
#pragma unroll
      for (int r = 0; r < 4; r++) {
        int row = m0 + tm * 16 + gp * 4 + r;
        Y[(size_t)row * 1024 + col] = acc[tm][tn][r] + bv_;
      }
  }
}

// ---------------- fused flash attention: ILP-structured, barrier-free ----------------
// 4 waves x 16 queries; grid (32,32). launch_bounds(256,3): VGPR cap ~168 so the K
// double-buffer + V tile + oacc all stay in registers (round-4's (128,6) -> 36 VGPR
// serialized every load; this is the fix).
// Pass-1 body: use CUR K-frags, prefetch NXT; lane-local running (m,l).
#define P1_BODY(CUR, NXT, KB)                                                         \
  do {                                                                                \
    _Pragma("unroll") for (int tn = 0; tn < 4; tn++) {                                \
      NXT[2 * tn] = *(const bf16x8*)(kp + tn * 1024);                                 \
      NXT[2 * tn + 1] = *(const bf16x8*)(kp + tn * 1024 + 32);                        \
    }                                                                                 \
    kp += 4096;                                                                       \
    float sv[4];                                                                      \
    _Pragma("unroll") for (int tn = 0; tn < 4; tn++) sv[tn] = sp2[(KB) + tn * 16];    \
    f32x4 st[4];                                                                      \
    _Pragma("unroll") for (int tn = 0; tn < 4; tn++) {                                \
      f32x4 s = {};                                                                   \
      s = MFMA(aQ0, CUR[2 * tn], s);                                                  \
      s = MFMA(aQ1, CUR[2 * tn + 1], s);                                              \
      st[tn] = s;                                                                     \
    }                                                                                 \
    _Pragma("unroll") for (int tn = 0; tn < 4; tn++)                                  \
        _Pragma("unroll") for (int r = 0; r < 4; r++) st[tn][r] =                     \
            st[tn][r] * 0.125f + sv[tn];                                              \
    _Pragma("unroll") for (int r = 0; r < 4; r++) {                                   \
      float v = fmaxf(fmaxf(st[0][r], st[1][r]), fmaxf(st[2][r], st[3][r]));          \
      float mn = fmaxf(ml[r], v);                                                     \
      float alpha = __expf(ml[r] - mn);                                               \
      ml[r] = mn;                                                                     \
      float s0 = __expf(st[0][r] - mn) + __expf(st[1][r] - mn) +                      \
                 __expf(st[2][r] - mn) + __expf(st[3][r] - mn);                       \
      ll[r] = ll[r] * alpha + s0;                                                     \
    }                                                                                 \
  } while (0)

// Pass-2 body: prefetch NXT K; QK from CUR; V loads issued BEFORE attn stores so the
// vmcnt FIFO wait for V never drains the stores; LDS transpose is per-wave (no barrier).
#define P2_BODY(CUR, NXT, KB)                                                         \
  do {                                                                                \
    _Pragma("unroll") for (int tn = 0; tn < 4; tn++) {                                \
      NXT[2 * tn] = *(const bf16x8*)(kp + tn * 1024);                                 \
      NXT[2 * tn + 1] = *(const bf16x8*)(kp + tn * 1024 + 32);                        \
    }                                                                                 \
    kp += 4096;                                                                       \
    f32x4 st[4];                                                                      \
    _Pragma("unroll") for (int tn = 0; tn < 4; tn++) {                                \
      f32x4 s = {};                                                                   \
      s = MFMA(aQ0, CUR[2 * tn], s);                                                  \
      s = MFMA(aQ1, CUR[2 * tn + 1], s);                                              \
      st[tn] = s;                                                                     \
    }                                                                                 \
    bf16x8 vc[8];                                                                     \
    _Pragma("unroll") for (int tn = 0; tn < 4; tn++) {                                \
      vc[2 * tn] = *(const bf16x8*)(vb + tn * 32768 + (KB));                          \
      vc[2 * tn + 1] = *(const bf16x8*)(vb + tn * 32768 + (KB) + 32);                 \
    }                                                                                 \
    float sv[4];                                                                      \
    _Pragma("unroll") for (int tn = 0; tn < 4; tn++) sv[tn] = sp2[(KB) + tn * 16];    \
    _Pragma("unroll") for (int tn = 0; tn < 4; tn++) {                                \
      _Pragma("unroll") for (int r = 0; r < 4; r++) {                                 \
        float p = __expf(st[tn][r] * 0.125f + sv[tn] - m[r]);                         \
        pr[r][tn * 16] = p * il[r];                                                   \
        pw[(gp * 4 + r) * 72 + tn * 16 + cl] = f2bf(p);                               \
      }                                                                               \
    }                                                                                 \
    _Pragma("unroll") for (int r = 0; r < 4; r++) pr[r] += 64;                        \
    asm volatile("s_waitcnt lgkmcnt(0)" ::: "memory");                                \
    __builtin_amdgcn_sched_barrier(0);                                                \
    bf16x8 aP0 = *(const bf16x8*)(pw + cl * 72 + gp * 8);                             \
    bf16x8 aP1 = *(const bf16x8*)(pw + cl * 72 + 32 + gp * 8);                        \
    asm volatile("" ::: "memory");                                                    \
    _Pragma("unroll") for (int tn = 0; tn < 4; tn++) {                                \
      oacc[tn] = MFMA(aP0, vc[2 * tn], oacc[tn]);                                     \
      oacc[tn] = MFMA(aP1, vc[2 * tn + 1], oacc[tn]);                                 \
    }                                                                                 \
  } while (0)

__global__ __launch_bounds__(256, 3) void flash_fused(const u16* __restrict__ Qb,
                                                      const u16* __restrict__ Kb,
                                                      const u16* __restrict__ Vt,
                                                      const float* __restrict__ sal,
                                                      float* __restrict__ attn,
                                                      u16* __restrict__ Ob) {
  __shared__ __align__(16) u16 pbuf[4][16][72];  // per-wave 16x64 P tile, stride 72
  const int bh = blockIdx.x;
  const int b = bh >> 4, h = bh & 15;
  const int lane = threadIdx.x & 63, wid = threadIdx.x >> 6;
  const int cl = lane & 15, gp = lane >> 4;
  const int q0 = blockIdx.y * 64 + wid * 16;
  const u16* Qh = Qb + (size_t)bh * 2048 * 64;
  const u16* Kh = Kb + (size_t)bh * 2048 * 64;
  const u16* Vh = Vt + (size_t)bh * 64 * 2048;
  const float* sp2 = sal + bh * 2048 + cl;
  bf16x8 aQ0 = *(const bf16x8*)(Qh + (size_t)(q0 + cl) * 64 + gp * 8);
  bf16x8 aQ1 = *(const bf16x8*)(Qh + (size_t)(q0 + cl) * 64 + 32 + gp * 8);
  const u16* kbase = Kh + cl * 64 + gp * 8;  // frag(tn) = kbase + kb*64 + tn*1024 (+32)
  const u16* vb = Vh + cl * 2048 + gp * 8;   // frag(tn) = vb + tn*32768 + kb (+32)

  // ---- pass 1: QK^T -> lane-local running (m,l); K reg double-buffered ----
  float ml[4], ll[4];
#pragma unroll
  for (int r = 0; r < 4; r++) { ml[r] = -1e30f; ll[r] = 0.f; }
  bf16x8 ka[8], kbg[8];
  const u16* kp = kbase;
#pragma unroll
  for (int tn = 0; tn < 4; tn++) {
    ka[2 * tn] = *(const bf16x8*)(kp + tn * 1024);
    ka[2 * tn + 1] = *(const bf16x8*)(kp + tn * 1024 + 32);
  }
  kp += 4096;
  // NOTE: last prefetch reads <=4KB past this head's K rows (lands in next region of
  // the contiguous workspace; values unused) — avoids a branch in the hot loop.
  for (int kb = 0; kb < 2048; kb += 128) {
    P1_BODY(ka, kbg, kb);
    P1_BODY(kbg, ka, kb + 64);
  }
  float m[4], il[4];
#pragma unroll
  for (int r = 0; r < 4; r++) {
    float mr = ml[r];
    mr = fmaxf(mr, __shfl_xor(mr, 1));
    mr = fmaxf(mr, __shfl_xor(mr, 2));
    mr = fmaxf(mr, __shfl_xor(mr, 4));
    mr = fmaxf(mr, __shfl_xor(mr, 8));
    float lr = ll[r] * __expf(ml[r] - mr);
    lr += __shfl_xor(lr, 1);
    lr += __shfl_xor(lr, 2);
    lr += __shfl_xor(lr, 4);
    lr += __shfl_xor(lr, 8);
    m[r] = mr;
    il[r] = 1.0f / lr;
  }

  // ---- pass 2: recompute S, stream attn (incremental row pointers), PV ----
  f32x4 oacc[4] = {};
  float* pr[4];
#pragma unroll
  for (int r = 0; r < 4; r++)
    pr[r] = attn + (size_t)bh * 2048 * 2048 + (size_t)(q0 + gp * 4 + r) * 2048 + cl;
  u16* pw = &pbuf[wid][0][0];
  kp = kbase;
#pragma unroll
  for (int tn = 0; tn < 4; tn++) {
    ka[2 * tn] = *(const bf16x8*)(kp + tn * 1024);
    ka[2 * tn + 1] = *(const bf16x8*)(kp + tn * 1024 + 32);
  }
  kp += 4096;
  for (int kb = 0; kb < 2048; kb += 128) {
    P2_BODY(ka, kbg, kb);
    P2_BODY(kbg, ka, kb + 64);
  }
#pragma unroll
  for (int tn = 0; tn < 4; tn++) {
    int d = h * 64 + tn * 16 + cl;
#pragma unroll
    for (int r = 0; r < 4; r++) {
      int q = q0 + gp * 4 + r;
      Ob[((size_t)(b * 2048 + q)) * 1024 + d] = f2bf(oacc[tn][r] * il[r]);
    }
  }
}

// ---------------- launch ----------------
extern "C" void kernel_launch(void* const* d_in, const int* in_sizes, int n_in,
                              void* d_out, int out_size, void* d_ws, size_t ws_size,
                              hipStream_t stream) {
  const float* src = (const float*)d_in[0];
  const float* Wq = (const float*)d_in[1];
  const float* bq = (const float*)d_in[2];
  const float* Wk = (const float*)d_in[3];
  const float* bk = (const float*)d_in[4];
  const float* Wv = (const float*)d_in[5];
  const float* bv = (const float*)d_in[6];
  const float* Wo = (const float*)d_in[7];
  const float* bo = (const float*)d_in[8];
  const float* cw = (const float*)d_in[9];
  const float* cb = (const float*)d_in[10];

  char* ws = (char*)d_ws;
  u16* srcb = (u16*)(ws + 0);          // 8,388,608 B
  u16* wqb = (u16*)(ws + 8388608);     // 2,097,152 B
  u16* wkb = (u16*)(ws + 10485760);
  u16* wvb = (u16*)(ws + 12582912);
  u16* wob = (u16*)(ws + 14680064);
  u16* Qb = (u16*)(ws + 16777216);     // 8,388,608 B  [B,H,L,64] bf16
  u16* Kb = (u16*)(ws + 25165824);
  u16* Vt = (u16*)(ws + 33554432);     // [B,H,64,L] bf16
  u16* Ob = (u16*)(ws + 41943040);     // [B,L,D] bf16
  float* cwT = (float*)(ws + 50331648);
  float* sal = (float*)(ws + 50528256);  // end 50,790,400

  float* outp = (float*)d_out;
  float* attn = (float*)d_out + 4194304;

  prep_all<<<8384, 256, 0, stream>>>((const float4*)src, (const float4*)Wq, (const float4*)Wk,
                                     (const float4*)Wv, (const float4*)Wo, cw,
                                     (uint2*)srcb, (uint2*)wqb, (uint2*)wkb, (uint2*)wvb,
                                     (uint2*)wob, cwT);
  conv_sal_k<<<dim3(512, 2), 256, 0, stream>>>(src, cwT, cb, sal);
  qkv_gemm<<<dim3(24, 32), 256, 0, stream>>>(srcb, wqb, wkb, wvb, bq, bk, bv, Qb, Kb, Vt);
  flash_fused<<<dim3(32, 32), 256, 0, stream>>>(Qb, Kb, Vt, sal, attn, Ob);
  out_gemm<<<dim3(8, 32), 256, 0, stream>>>(Ob, wob, bo, outp);
}